// Round 2
// baseline (246.238 us; speedup 1.0000x reference)
//
#include <hip/hip_runtime.h>

#define FEAT 128
#define HID  128
#define XS_S 132  // 128 nodes + 4 pad; even -> 8B-aligned float2 reads

// ---------------------------------------------------------------------------
// Kernel 1: [A|B] = X @ [W1[:128] | W1[128:]]  (N x 256 concat, fp32)
// Wave-uniform-W mapping: lane l owns nodes (2l, 2l+1); wave w owns 16
// wave-uniform output cols. Block = 128 nodes x 64 concat-cols (4 waves).
// Per k: ONE ds_read_b64 for X (512 B/wave, 0.28 B/FMA) + 4 wave-uniform
// float4 loads of W straight from global (readfirstlane'd col offset ->
// scalar/broadcast loads, L1/K$-resident 128 KB). No W staging in LDS at
// all -> the LDS pipe (the round-1 bottleneck: 1.25 B/FMA vs ~1 B/cyc/FMA
// capacity) is now ~5x under budget -> VALU-bound.
// LDS 16.9 KB, ~64 VGPR -> 6+ blocks/CU. Grid 1564 linear, bijective
// XCD-chunked swizzle keeps the 4 col-group blocks of one X-tile
// back-to-back on the same XCD (X fetched ~once: 13 MB FETCH in round 1).
// b1 folded into the A-half epilogue.
// ---------------------------------------------------------------------------
__global__ __launch_bounds__(256) void gemm_ab(
    const float* __restrict__ X, const float* __restrict__ W1,
    const float* __restrict__ b1, float* __restrict__ A,
    float* __restrict__ B, int N) {
  __shared__ float xs[32 * XS_S];
  const int t = threadIdx.x;

  // bijective chunked XCD swizzle (nb need not be %8==0)
  const int nb = gridDim.x;
  const int q = nb >> 3, r = nb & 7;
  const int xcd = blockIdx.x & 7, bidx = blockIdx.x >> 3;
  const int nw = (xcd < r ? xcd * (q + 1) : r * (q + 1) + (xcd - r) * q) + bidx;
  const int n0 = (nw >> 2) * 128;
  const int jb = (nw & 3) * 64;   // concat col base: 0,64 -> A ; 128,192 -> B
  const int isA = jb < 128;
  const int ob = jb & 127;        // col base within the half
  const float* Wb = W1 + (size_t)(isA ? 0 : 128 * HID) + ob;
  float* Obase = isA ? A : B;

  const int l = t & 63;
  // wave-uniform column offset: lets the compiler use scalar/broadcast loads
  const int wv16 = __builtin_amdgcn_readfirstlane((t >> 6) * 16);
  const float* Wp = Wb + wv16;

  float acc0[16], acc1[16];
#pragma unroll
  for (int c = 0; c < 16; ++c) { acc0[c] = 0.f; acc1[c] = 0.f; }

  const int ln = t >> 3;       // staging node 0..31 (+rep*32)
  const int lf = (t & 7) * 4;  // staging k-local float4 base

  for (int kc = 0; kc < 4; ++kc) {
    __syncthreads();
    // stage X chunk transposed: xs[k_local][node]
#pragma unroll
    for (int rep = 0; rep < 4; ++rep) {
      const int nl = ln + rep * 32;
      const int n = n0 + nl;
      float4 v = make_float4(0.f, 0.f, 0.f, 0.f);
      if (n < N) v = *(const float4*)(X + (size_t)n * FEAT + kc * 32 + lf);
      xs[(lf + 0) * XS_S + nl] = v.x;
      xs[(lf + 1) * XS_S + nl] = v.y;
      xs[(lf + 2) * XS_S + nl] = v.z;
      xs[(lf + 3) * XS_S + nl] = v.w;
    }
    __syncthreads();

#pragma unroll 4
    for (int k = 0; k < 32; ++k) {
      const float2 xv = *(const float2*)&xs[k * XS_S + 2 * l];
      const float* wr = Wp + (size_t)(kc * 32 + k) * HID;
      float wv[16];
      *(float4*)&wv[0]  = *(const float4*)(wr);
      *(float4*)&wv[4]  = *(const float4*)(wr + 4);
      *(float4*)&wv[8]  = *(const float4*)(wr + 8);
      *(float4*)&wv[12] = *(const float4*)(wr + 12);
#pragma unroll
      for (int c = 0; c < 16; ++c) {
        acc0[c] = fmaf(xv.x, wv[c], acc0[c]);
        acc1[c] = fmaf(xv.y, wv[c], acc1[c]);
      }
    }
  }

  // epilogue: fold b1 into the A-half so edge_z needn't read it
  float4 bb[4];
#pragma unroll
  for (int c = 0; c < 4; ++c) bb[c] = make_float4(0.f, 0.f, 0.f, 0.f);
  if (isA) {
#pragma unroll
    for (int c = 0; c < 4; ++c)
      bb[c] = *(const float4*)(b1 + ob + wv16 + c * 4);
  }
  const int na = n0 + 2 * l;
  const int nbb = na + 1;
  if (na < N) {
    float* o = Obase + (size_t)na * HID + ob + wv16;
#pragma unroll
    for (int c = 0; c < 4; ++c)
      *(float4*)(o + c * 4) = make_float4(
          acc0[c * 4 + 0] + bb[c].x, acc0[c * 4 + 1] + bb[c].y,
          acc0[c * 4 + 2] + bb[c].z, acc0[c * 4 + 3] + bb[c].w);
  }
  if (nbb < N) {
    float* o = Obase + (size_t)nbb * HID + ob + wv16;
#pragma unroll
    for (int c = 0; c < 4; ++c)
      *(float4*)(o + c * 4) = make_float4(
          acc1[c * 4 + 0] + bb[c].x, acc1[c * 4 + 1] + bb[c].y,
          acc1[c * 4 + 2] + bb[c].z, acc1[c * 4 + 3] + bb[c].w);
  }
}

// ---------------------------------------------------------------------------
// Kernel 2: CSR row offsets from sorted src via binary search. rs has N+1 ents.
// ---------------------------------------------------------------------------
__global__ __launch_bounds__(256) void row_offsets(
    const int* __restrict__ src, int* __restrict__ rs, int N, int E) {
  const int n = blockIdx.x * 256 + threadIdx.x;
  if (n > N) return;
  int lo = 0, hi = E;
  while (lo < hi) {
    const int mid = (lo + hi) >> 1;
    if (src[mid] < n) lo = mid + 1; else hi = mid;
  }
  rs[n] = lo;
}

// ---------------------------------------------------------------------------
// Kernel 3: z[e] = W2 . relu(A[src[e]] + B[dst[e]]) + b2   (b1 pre-folded in A)
// 16 lanes per edge (8 floats/lane), 2 edges per 16-lane group, all 8 row
// loads issued before any reduce. 4-step shfl_xor reduce.
// ---------------------------------------------------------------------------
__global__ __launch_bounds__(256) void edge_z(
    const float* __restrict__ A, const float* __restrict__ B,
    const float* __restrict__ W2, const float* __restrict__ b2,
    const int* __restrict__ src, const int* __restrict__ dst,
    float* __restrict__ z, int E) {
  const int g = threadIdx.x >> 4;
  const int l = threadIdx.x & 15;
  const int e0 = blockIdx.x * 32 + g * 2;
  if (e0 >= E) return;
  const int e1 = e0 + 1;
  const bool has1 = e1 < E;

  const int u0 = src[e0], v0 = dst[e0];
  const int u1 = has1 ? src[e1] : u0;
  const int v1 = has1 ? dst[e1] : v0;

  const float4* Au0 = (const float4*)(A + (size_t)u0 * HID) + l * 2;
  const float4* Bv0 = (const float4*)(B + (size_t)v0 * HID) + l * 2;
  const float4* Au1 = (const float4*)(A + (size_t)u1 * HID) + l * 2;
  const float4* Bv1 = (const float4*)(B + (size_t)v1 * HID) + l * 2;

  const float4 a00 = Au0[0], a01 = Au0[1];
  const float4 b00 = Bv0[0], b01 = Bv0[1];
  const float4 a10 = Au1[0], a11 = Au1[1];
  const float4 b10 = Bv1[0], b11 = Bv1[1];

  const float4 w0 = *(const float4*)(W2 + l * 8);
  const float4 w1 = *(const float4*)(W2 + l * 8 + 4);
  const float bias2 = b2[0];

  float p0 = fmaxf(a00.x + b00.x, 0.f) * w0.x
           + fmaxf(a00.y + b00.y, 0.f) * w0.y
           + fmaxf(a00.z + b00.z, 0.f) * w0.z
           + fmaxf(a00.w + b00.w, 0.f) * w0.w
           + fmaxf(a01.x + b01.x, 0.f) * w1.x
           + fmaxf(a01.y + b01.y, 0.f) * w1.y
           + fmaxf(a01.z + b01.z, 0.f) * w1.z
           + fmaxf(a01.w + b01.w, 0.f) * w1.w;
  float p1 = fmaxf(a10.x + b10.x, 0.f) * w0.x
           + fmaxf(a10.y + b10.y, 0.f) * w0.y
           + fmaxf(a10.z + b10.z, 0.f) * w0.z
           + fmaxf(a10.w + b10.w, 0.f) * w0.w
           + fmaxf(a11.x + b11.x, 0.f) * w1.x
           + fmaxf(a11.y + b11.y, 0.f) * w1.y
           + fmaxf(a11.z + b11.z, 0.f) * w1.z
           + fmaxf(a11.w + b11.w, 0.f) * w1.w;

#pragma unroll
  for (int m = 8; m >= 1; m >>= 1) {
    p0 += __shfl_xor(p0, m);
    p1 += __shfl_xor(p1, m);
  }
  if (l == 0) {
    z[e0] = p0 + bias2;
    if (has1) z[e1] = p1 + bias2;
  }
}

// ---------------------------------------------------------------------------
// Kernel 4: per-node log-softmax + K Gumbel rounds. FOUR nodes per wave:
// 16 lanes per node, 2 edges per lane (covers deg<=32; avg deg 16). 4-step
// shfl_xor reduces serve 4 nodes per DS instruction. Works in ex = exp(s)
// space: argmax(ex) == argmax(s); fast __logf/__expf.
// ---------------------------------------------------------------------------
__global__ __launch_bounds__(256) void seg_sample(
    const float* __restrict__ z, const float* __restrict__ U,
    const int* __restrict__ dst, const int* __restrict__ rs,
    float* __restrict__ out_sel, float* __restrict__ out_soft,
    int N, int E, int K) {
  const int t = threadIdx.x;
  const int lane = t & 63;
  const int qtr = lane >> 4;   // quarter 0..3: one node each
  const int ql = lane & 15;    // lane within node: edges 2*ql, 2*ql+1
  const int n = blockIdx.x * 16 + (t >> 6) * 4 + qtr;
  const float INVTAU = 1.0f / 0.9991f;

  int start = 0, deg = 0;
  if (n < N) { start = rs[n]; deg = rs[n + 1] - start; }

  if (__all(deg <= 32)) {
    // ---- fast path: 16-lane quarter per node, 2 edges/lane ----
    if (n >= N) return;
    if (deg == 0) {
      if (ql == 0)
        for (int k = 0; k < K; ++k) out_sel[(size_t)k * N + n] = -2147483648.0f;
      return;
    }
    const bool a0 = 2 * ql < deg;
    const bool a1 = 2 * ql + 1 < deg;
    const int e0 = start + 2 * ql;
    const int e1 = e0 + 1;
    const float z0 = a0 ? z[e0] : -INFINITY;
    const float z1 = a1 ? z[e1] : -INFINITY;
    const int d0 = a0 ? dst[e0] : -1;
    const int d1 = a1 ? dst[e1] : -1;

    float zmax = fmaxf(z0, z1);
#pragma unroll
    for (int m = 8; m >= 1; m >>= 1) zmax = fmaxf(zmax, __shfl_xor(zmax, m));
    float den = (a0 ? __expf(z0 - zmax) : 0.f) + (a1 ? __expf(z1 - zmax) : 0.f);
#pragma unroll
    for (int m = 8; m >= 1; m >>= 1) den += __shfl_xor(den, m);
    const float logd = __logf(den);
    const float lp0 = (z0 - zmax) - logd;  // per-edge log-prob
    const float lp1 = (z1 - zmax) - logd;

    for (int k = 0; k < K; ++k) {
      float ex0 = 0.f, ex1 = 0.f;
      if (a0) {
        const float uu = U[(size_t)k * E + e0];
        const float gum = -__logf(-__logf(uu));
        ex0 = __expf((lp0 + gum) * INVTAU);  // exp(s); s in [-19,15] -> safe
      }
      if (a1) {
        const float uu = U[(size_t)k * E + e1];
        const float gum = -__logf(-__logf(uu));
        ex1 = __expf((lp1 + gum) * INVTAU);
      }
      // lane-local pair combine (tie -> larger dst, matching reference)
      float d2 = ex0 + ex1;
      float mx;
      int md;
      if (ex1 > ex0)      { mx = ex1; md = d1; }
      else if (ex1 < ex0) { mx = ex0; md = d0; }
      else                { mx = ex0; md = max(d0, d1); }
#pragma unroll
      for (int m = 8; m >= 1; m >>= 1) {
        d2 += __shfl_xor(d2, m);
        const float ox = __shfl_xor(mx, m);
        const int od = __shfl_xor(md, m);
        if (ox > mx) { mx = ox; md = od; }
        else if (ox == mx) md = max(md, od);
      }
      if (ql == 0) out_sel[(size_t)k * N + n] = (float)md;
      const float inv = __builtin_amdgcn_rcpf(d2);
      if (a0) out_soft[(size_t)k * E + e0] = ex0 * inv;
      if (a1) out_soft[(size_t)k * E + e1] = ex1 * inv;
    }
    return;
  }

  // ---- general path (some deg > 32, ~5 nodes): full wave per node, x4 ----
  const int wbase = blockIdx.x * 16 + (t >> 6) * 4;
  for (int j = 0; j < 4; ++j) {
    const int nn = wbase + j;
    if (nn >= N) continue;
    const int st = rs[nn];
    const int dg = rs[nn + 1] - st;
    if (dg == 0) {
      if (lane == 0)
        for (int k = 0; k < K; ++k) out_sel[(size_t)k * N + nn] = -2147483648.0f;
      continue;
    }
    float zmax = -INFINITY;
    for (int c = lane; c < dg; c += 64) zmax = fmaxf(zmax, z[st + c]);
#pragma unroll
    for (int m = 32; m >= 1; m >>= 1) zmax = fmaxf(zmax, __shfl_xor(zmax, m));
    float den = 0.f;
    for (int c = lane; c < dg; c += 64) den += expf(z[st + c] - zmax);
#pragma unroll
    for (int m = 32; m >= 1; m >>= 1) den += __shfl_xor(den, m);
    const float logd = logf(den);

    for (int k = 0; k < K; ++k) {
      float m2 = -INFINITY;
      for (int c = lane; c < dg; c += 64) {
        const int e = st + c;
        const float gum = -logf(-logf(U[(size_t)k * E + e]));
        const float s = ((z[e] - zmax) - logd + gum) * INVTAU;
        m2 = fmaxf(m2, s);
      }
#pragma unroll
      for (int m = 32; m >= 1; m >>= 1) m2 = fmaxf(m2, __shfl_xor(m2, m));
      float d2 = 0.f;
      int cand = -1;
      for (int c = lane; c < dg; c += 64) {
        const int e = st + c;
        const float gum = -logf(-logf(U[(size_t)k * E + e]));
        const float s = ((z[e] - zmax) - logd + gum) * INVTAU;
        d2 += expf(s - m2);
        if (s >= m2) cand = max(cand, dst[e]);
      }
#pragma unroll
      for (int m = 32; m >= 1; m >>= 1) d2 += __shfl_xor(d2, m);
#pragma unroll
      for (int m = 32; m >= 1; m >>= 1) cand = max(cand, __shfl_xor(cand, m));
      if (lane == 0) out_sel[(size_t)k * N + nn] = (float)cand;
      for (int c = lane; c < dg; c += 64) {
        const int e = st + c;
        const float gum = -logf(-logf(U[(size_t)k * E + e]));
        const float s = ((z[e] - zmax) - logd + gum) * INVTAU;
        out_soft[(size_t)k * E + e] = expf(s - m2) / d2;
      }
    }
  }
}

// ---------------------------------------------------------------------------
extern "C" void kernel_launch(void* const* d_in, const int* in_sizes, int n_in,
                              void* d_out, int out_size, void* d_ws, size_t ws_size,
                              hipStream_t stream) {
  const float* X  = (const float*)d_in[0];  // (N, 128)
  const float* W1 = (const float*)d_in[1];  // (256, 128)
  const float* b1 = (const float*)d_in[2];  // (128,)
  const float* W2 = (const float*)d_in[3];  // (128,)
  const float* b2 = (const float*)d_in[4];  // (1,)
  const float* U  = (const float*)d_in[5];  // (K, E)
  const int* src  = (const int*)d_in[6];    // (E,) sorted
  const int* dst  = (const int*)d_in[7];    // (E,)
  const int E = in_sizes[6];
  const int K = in_sizes[5] / E;
  const int N = in_sizes[0] / FEAT;

  // workspace: A (N*128 f32) | B (N*128 f32) | z (E f32) | rs (N+1 i32)
  float* A = (float*)d_ws;
  float* B = A + (size_t)N * HID;
  float* z = B + (size_t)N * HID;
  int* rs  = (int*)(z + E);

  float* out_sel  = (float*)d_out;                  // (K, N) as f32
  float* out_soft = (float*)d_out + (size_t)K * N;  // (K, E)

  hipLaunchKernelGGL(gemm_ab, dim3(4 * ((N + 127) / 128)), dim3(256), 0, stream,
                     X, W1, b1, A, B, N);
  hipLaunchKernelGGL(row_offsets, dim3((N + 256) / 256), dim3(256), 0, stream,
                     src, rs, N, E);
  hipLaunchKernelGGL(edge_z, dim3((E + 31) / 32), dim3(256), 0, stream,
                     A, B, W2, b2, src, dst, z, E);
  hipLaunchKernelGGL(seg_sample, dim3((N + 15) / 16), dim3(256), 0, stream,
                     z, U, dst, rs, out_sel, out_soft, N, E, K);
}